// Round 7
// baseline (276.414 us; speedup 1.0000x reference)
//
#include <hip/hip_runtime.h>

// FeatureExtractor: out = concat([x, |ifft2(low)|/max, |ifft2(high)|/max], axis=1)
// x: (32,3,512,512) fp32. Mask keeps 45 freq bins (|ky|,|kx|<=3, ky^2+kx^2<16).
// Low-pass signal s is REAL (symmetric mask, real input); hp = |x - s|.
// Pipeline: K1 row-DFT -> K2 col-DFT + Rtab (REWRITTEN: 512 thr, bin-parallel)
//           K3 maxes + channel-0 x-copy -> K4 lp/hp write.
// R7 ATTRIBUTION: K4 launched 3x (idempotent) -> K4_dur = (dur - prev + dK2)/2.

#define NN 512
#define IMGS 96
constexpr float TWOPI_N = 6.2831853071795864769f / 512.0f;
constexpr float INV_N2  = 1.0f / (512.0f * 512.0f);

// workspace layout (bytes)
#define G_OFF   0                              // 96*512*8 floats = 1,572,864 B
#define R_OFF   (96 * 512 * 8 * 4)             // Rtab: 96*512*8 floats = 1,572,864 B
#define MAX_OFF (R_OFF + 96 * 512 * 8 * 4)     // 2 uints
#define WS_NEEDED (MAX_OFF + 8)

// ---------------- K1: per-row DFT at kx=0..3 (4 rows/wave, 16 lanes/row) ----
__global__ __launch_bounds__(256) void k1_rowfft(const float* __restrict__ x,
                                                 float* __restrict__ G,
                                                 unsigned int* __restrict__ maxes) {
  const int tid = threadIdx.x;
  if (blockIdx.x == 0 && blockIdx.y == 0 && tid == 0) {
    maxes[0] = 0u; maxes[1] = 0u;   // fold memset into K1 (K3 runs later in stream)
  }
  const int img = blockIdx.y;
  const int row = blockIdx.x * 16 + ((tid >> 6) << 2) + ((tid & 63) >> 4);
  const int l16 = tid & 15;
  const float* xr = x + (((size_t)img) << 18) + row * NN;

  float gr0 = 0.f, gr1 = 0.f, gi1 = 0.f, gr2 = 0.f, gi2 = 0.f, gr3 = 0.f, gi3 = 0.f;
  const float cd  = 0.99992470183914454f;    // cos(2pi/512)
  const float sd  = 0.012271538285719925f;   // sin(2pi/512)
  const float r45 = 0.70710678118654752f;    // cos(pi/4) = sin(pi/4), EXACT rotation/iter
  float c, s;
  __sincosf(TWOPI_N * (float)(l16 * 4), &s, &c);
  #pragma unroll
  for (int it = 0; it < 8; ++it) {
    const float4 xv = *reinterpret_cast<const float4*>(xr + it * 64 + l16 * 4);
    const float xe[4] = {xv.x, xv.y, xv.z, xv.w};
    float cc = c, ss = s;
    #pragma unroll
    for (int j = 0; j < 4; ++j) {
      const float c2 = cc * cc - ss * ss, s2 = 2.f * cc * ss;
      const float c3 = cc * c2 - ss * s2, s3 = ss * c2 + cc * s2;
      const float xx = xe[j];
      gr0 += xx;
      gr1 = fmaf(xx, cc, gr1);  gi1 = fmaf(-xx, ss, gi1);   // e^{-i*1*theta}
      gr2 = fmaf(xx, c2, gr2);  gi2 = fmaf(-xx, s2, gi2);
      gr3 = fmaf(xx, c3, gr3);  gi3 = fmaf(-xx, s3, gi3);
      const float cn = cc * cd - ss * sd;
      const float sn = ss * cd + cc * sd;
      cc = cn; ss = sn;
    }
    const float cN = r45 * (c - s);   // advance base by 64 columns = pi/4, exact
    const float sN = r45 * (c + s);
    c = cN; s = sN;
  }
  #pragma unroll
  for (int off = 8; off; off >>= 1) {
    gr0 += __shfl_down(gr0, off);
    gr1 += __shfl_down(gr1, off); gi1 += __shfl_down(gi1, off);
    gr2 += __shfl_down(gr2, off); gi2 += __shfl_down(gi2, off);
    gr3 += __shfl_down(gr3, off); gi3 += __shfl_down(gi3, off);
  }
  if (l16 == 0) {
    float* g = G + (size_t)(img * 512 + row) * 8;
    *reinterpret_cast<float4*>(g)     = make_float4(gr0, 0.f, gr1, gi1);
    *reinterpret_cast<float4*>(g + 4) = make_float4(gr2, gi2, gr3, gi3);
  }
}

// ---------------- K2 (rewritten): bin-parallel col-DFT -> Rtab ----------------
// 512 threads/img. Stage G (16 KB) into padded LDS; 28 bins x 18 threads each
// accumulate ~29 u-terms with direct sincos((ky*u) mod 512); LDS tree reduce;
// 512-thread Rtab build (one x per thread).
__global__ __launch_bounds__(512) void k2_colfft(const float* __restrict__ G,
                                                 float* __restrict__ Rtab) {
  const int img = blockIdx.x;
  const int tid = threadIdx.x;
  __shared__ float sG[512][9];          // 8 cols used + 1 pad (bank spread)
  __shared__ float parts[28][18][2];
  __shared__ float Ff[56];

  {  // stage G for this image
    const float* g = G + (size_t)img * 4096 + tid * 8;
    const float4 ga = *reinterpret_cast<const float4*>(g);
    const float4 gb = *reinterpret_cast<const float4*>(g + 4);
    sG[tid][0] = ga.x; sG[tid][1] = ga.y; sG[tid][2] = ga.z; sG[tid][3] = ga.w;
    sG[tid][4] = gb.x; sG[tid][5] = gb.y; sG[tid][6] = gb.z; sG[tid][7] = gb.w;
  }
  __syncthreads();

  if (tid < 504) {
    const int b = tid / 18;          // bin 0..27  (ky = b/7, kxs = b%7)
    const int k = tid % 18;
    const int ky = b / 7, kxs = b % 7;
    const int a = (kxs < 3) ? (3 - kxs) : (kxs - 3);
    const float sgn = (kxs < 3) ? -1.f : 1.f;   // G[u,-k] = conj(G[u,k])
    float pr = 0.f, pi = 0.f;
    for (int u = k; u < 512; u += 18) {
      const float gr = sG[u][a * 2];
      const float gi = sgn * sG[u][a * 2 + 1];  // sG[u][1] == 0 for a==0
      const int m = (ky * u) & 511;             // exact period-512 reduction
      float cc, ss;
      __sincosf(TWOPI_N * (float)m, &ss, &cc);  // e^{-i ky u th} = (cc, -ss)
      pr += gr * cc + gi * ss;
      pi += gi * cc - gr * ss;
    }
    parts[b][k][0] = pr; parts[b][k][1] = pi;
  }
  __syncthreads();
  if (tid < 28) {
    float sr = 0.f, si = 0.f;
    #pragma unroll
    for (int k = 0; k < 18; ++k) { sr += parts[tid][k][0]; si += parts[tid][k][1]; }
    Ff[2 * tid] = sr; Ff[2 * tid + 1] = si;
  }
  __syncthreads();

  // per-x table: Rtab[x][8] = (R0, 2R1r, 2R1i, 2R2r, 2R2i, 2R3r, 2R3i, 0)/N^2
  float fr[28], fi[28];
  #pragma unroll
  for (int f = 0; f < 28; ++f) { fr[f] = Ff[2 * f]; fi[f] = Ff[2 * f + 1]; }
  const int xx = tid;                 // 512 threads -> one x each
  float c1, s1;
  __sincosf(TWOPI_N * (float)xx, &s1, &c1);
  const float c2 = c1 * c1 - s1 * s1, s2 = 2.f * c1 * s1;
  const float c3 = c1 * c2 - s1 * s2, s3 = s1 * c2 + c1 * s2;
  const float pc[4] = {1.f, c1, c2, c3};
  const float ps[4] = {0.f, s1, s2, s3};
  float Rr[4], Ri[4];
  #pragma unroll
  for (int ky = 0; ky < 4; ++ky) {
    float rr = 0.f, ri = 0.f;
    #pragma unroll
    for (int kxs = 0; kxs < 7; ++kxs) {
      if (ky == 3 && (kxs == 0 || kxs == 6)) continue;  // 9+9 >= 16 excluded
      const int a = (kxs < 3) ? (3 - kxs) : (kxs - 3);
      const float ec = pc[a];
      const float es = (kxs < 3) ? -ps[a] : ps[a];      // e^{+i kx x th}
      const int f = ky * 7 + kxs;
      rr += fr[f] * ec - fi[f] * es;
      ri += fr[f] * es + fi[f] * ec;
    }
    Rr[ky] = rr; Ri[ky] = ri;
  }
  float* o = Rtab + (size_t)(img * 512 + xx) * 8;
  const float k2s = 2.f * INV_N2;
  *reinterpret_cast<float4*>(o) =
      make_float4(Rr[0] * INV_N2, Rr[1] * k2s, Ri[1] * k2s, Rr[2] * k2s);
  *reinterpret_cast<float4*>(o + 4) =
      make_float4(Ri[2] * k2s, Rr[3] * k2s, Ri[3] * k2s, 0.f);
}

// ---------------- shared per-block prologue for K3/K4 ----------------
__device__ __forceinline__ void load_ctx(const float* __restrict__ Rtab, int img,
                                         int xi, int ybase, int tid,
                                         float (*yt)[6], float4 Ra[4], float4 Rb[4]) {
  if (tid < 32) {
    const int y = ybase + tid;
    float c1, s1;
    __sincosf(TWOPI_N * (float)y, &s1, &c1);
    const float c2 = c1 * c1 - s1 * s1, s2 = 2.f * c1 * s1;
    const float c3 = c1 * c2 - s1 * s2, s3 = s1 * c2 + c1 * s2;
    yt[tid][0] = c1; yt[tid][1] = s1;
    yt[tid][2] = c2; yt[tid][3] = s2;
    yt[tid][4] = c3; yt[tid][5] = s3;
  }
  const float* rt = Rtab + (size_t)(img * 512 + xi) * 8;
  #pragma unroll
  for (int j = 0; j < 4; ++j) {
    Ra[j] = *reinterpret_cast<const float4*>(rt + j * 8);
    Rb[j] = *reinterpret_cast<const float4*>(rt + j * 8 + 4);
  }
  __syncthreads();
}

__device__ __forceinline__ float recon(const float4& Ra, const float4& Rb,
                                       const float* yy) {
  float S = Ra.x;
  S = fmaf(Ra.y,  yy[0], S); S = fmaf(-Ra.z, yy[1], S);
  S = fmaf(Ra.w,  yy[2], S); S = fmaf(-Rb.x, yy[3], S);
  S = fmaf(Rb.y,  yy[4], S); S = fmaf(-Rb.z, yy[5], S);
  return S;
}

// ---------------- K3: global maxes + channel-0 x-copy ----------------
__global__ __launch_bounds__(256) void k3_maxcopy(const float* __restrict__ x,
    const float* __restrict__ Rtab, unsigned int* __restrict__ maxes,
    float* __restrict__ out) {
  const int img = blockIdx.y;
  const int b = img / 3, c = img - b * 3;
  const int tid = threadIdx.x;
  const int xi = (tid & 127) * 4;
  const int p = tid >> 7;
  const int ybase = blockIdx.x * 32;
  __shared__ float yt[32][6];
  float4 Ra[4], Rb[4];
  load_ctx(Rtab, img, xi, ybase, tid, yt, Ra, Rb);
  const float* xim = x + (((size_t)img) << 18);
  float* o0 = out + (((size_t)(b * 9 + c)) << 18);
  float mlp = 0.f, mhp = 0.f;
  for (int it = 0; it < 16; ++it) {
    const int yy = it * 2 + p;
    const int y = ybase + yy;
    float yv[6];
    #pragma unroll
    for (int q = 0; q < 6; ++q) yv[q] = yt[yy][q];
    const float4 xv = *reinterpret_cast<const float4*>(xim + y * NN + xi);
    *reinterpret_cast<float4*>(o0 + y * NN + xi) = xv;   // channel-0 copy
    const float xe[4] = {xv.x, xv.y, xv.z, xv.w};
    #pragma unroll
    for (int j = 0; j < 4; ++j) {
      const float sig = recon(Ra[j], Rb[j], yv);
      mlp = fmaxf(mlp, fabsf(sig));
      mhp = fmaxf(mhp, fabsf(xe[j] - sig));
    }
  }
  #pragma unroll
  for (int off = 32; off; off >>= 1) {
    mlp = fmaxf(mlp, __shfl_down(mlp, off));
    mhp = fmaxf(mhp, __shfl_down(mhp, off));
  }
  __shared__ float sm[8];
  const int lane = tid & 63, wv = tid >> 6;
  if (lane == 0) { sm[wv * 2] = mlp; sm[wv * 2 + 1] = mhp; }
  __syncthreads();
  if (tid == 0) {
    const float a  = fmaxf(fmaxf(sm[0], sm[2]), fmaxf(sm[4], sm[6]));
    const float bb = fmaxf(fmaxf(sm[1], sm[3]), fmaxf(sm[5], sm[7]));
    atomicMax(&maxes[0], __float_as_uint(a));   // nonneg floats: bit order == value order
    atomicMax(&maxes[1], __float_as_uint(bb));
  }
}

// ---------------- K4: normalized lp/hp write ----------------
__global__ __launch_bounds__(256) void k4_write(const float* __restrict__ x,
    const float* __restrict__ Rtab, const unsigned int* __restrict__ maxes,
    float* __restrict__ out) {
  const int img = blockIdx.y;
  const int b = img / 3, c = img - b * 3;
  const int tid = threadIdx.x;
  const int xi = (tid & 127) * 4;
  const int p = tid >> 7;
  const int ybase = blockIdx.x * 32;
  __shared__ float yt[32][6];
  float4 Ra[4], Rb[4];
  load_ctx(Rtab, img, xi, ybase, tid, yt, Ra, Rb);
  const float inv_lp = 1.f / __uint_as_float(maxes[0]);
  const float inv_hp = 1.f / __uint_as_float(maxes[1]);
  const float* xim = x + (((size_t)img) << 18);
  float* o1 = out + (((size_t)(b * 9 + 3 + c)) << 18);
  float* o2 = out + (((size_t)(b * 9 + 6 + c)) << 18);
  for (int it = 0; it < 16; ++it) {
    const int yy = it * 2 + p;
    const int y = ybase + yy;
    float yv[6];
    #pragma unroll
    for (int q = 0; q < 6; ++q) yv[q] = yt[yy][q];
    const float4 xv = *reinterpret_cast<const float4*>(xim + y * NN + xi);
    const float xe[4] = {xv.x, xv.y, xv.z, xv.w};
    float4 lpv, hpv;
    float* lpa = &lpv.x;
    float* hpa = &hpv.x;
    #pragma unroll
    for (int j = 0; j < 4; ++j) {
      const float sig = recon(Ra[j], Rb[j], yv);
      lpa[j] = fabsf(sig) * inv_lp;
      hpa[j] = fabsf(xe[j] - sig) * inv_hp;
    }
    const int o = y * NN + xi;
    *reinterpret_cast<float4*>(o1 + o) = lpv;
    *reinterpret_cast<float4*>(o2 + o) = hpv;
  }
}

extern "C" void kernel_launch(void* const* d_in, const int* in_sizes, int n_in,
                              void* d_out, int out_size, void* d_ws, size_t ws_size,
                              hipStream_t stream) {
  if (ws_size < (size_t)WS_NEEDED) return;  // loud failure instead of corruption
  const float* x = (const float*)d_in[0];
  float* out = (float*)d_out;
  char* ws = (char*)d_ws;
  float* G = (float*)(ws + G_OFF);
  float* Rtab = (float*)(ws + R_OFF);
  unsigned int* maxes = (unsigned int*)(ws + MAX_OFF);

  k1_rowfft<<<dim3(32, IMGS), 256, 0, stream>>>(x, G, maxes);
  k2_colfft<<<dim3(IMGS), 512, 0, stream>>>(G, Rtab);
  k3_maxcopy<<<dim3(16, IMGS), 256, 0, stream>>>(x, Rtab, maxes, out);
  // ATTRIBUTION: K4 x3 (idempotent) -> K4_dur = (dur - dur_R6 + dK2) / 2
  k4_write<<<dim3(16, IMGS), 256, 0, stream>>>(x, Rtab, maxes, out);
  k4_write<<<dim3(16, IMGS), 256, 0, stream>>>(x, Rtab, maxes, out);
  k4_write<<<dim3(16, IMGS), 256, 0, stream>>>(x, Rtab, maxes, out);
}

// Round 8
// 175.152 us; speedup vs baseline: 1.5781x; 1.5781x over previous
//
#include <hip/hip_runtime.h>

// FeatureExtractor: out = concat([x, |ifft2(low)|/max, |ifft2(high)|/max], axis=1)
// x: (32,3,512,512) fp32. Mask keeps 45 freq bins (|ky|,|kx|<=3, ky^2+kx^2<16).
// Low-pass signal s is REAL (symmetric mask, real input); hp = |x - s|.
// Pipeline: K1 row-DFT -> K2 col-DFT + Rtab -> K3 maxes + ch0 copy -> K4 lp/hp.
// R8: measured K4=65us vs 44 floor, K3=45 vs 30. Fixes: (1) NT stores on ALL
// output (never re-read; keeps x L3-resident), (2) 2x blocks (16 rows each),
// (3) K4 one-channel-per-block (blockIdx.z) = clean 1-read/1-write streams.

#define NN 512
#define IMGS 96
constexpr float TWOPI_N = 6.2831853071795864769f / 512.0f;
constexpr float INV_N2  = 1.0f / (512.0f * 512.0f);

typedef float f4v __attribute__((ext_vector_type(4)));

// workspace layout (bytes)
#define G_OFF   0                              // 96*512*8 floats = 1,572,864 B
#define R_OFF   (96 * 512 * 8 * 4)             // Rtab: 96*512*8 floats = 1,572,864 B
#define MAX_OFF (R_OFF + 96 * 512 * 8 * 4)     // 2 uints
#define WS_NEEDED (MAX_OFF + 8)

// ---------------- K1: per-row DFT at kx=0..3 (4 rows/wave, 16 lanes/row) ----
__global__ __launch_bounds__(256) void k1_rowfft(const float* __restrict__ x,
                                                 float* __restrict__ G,
                                                 unsigned int* __restrict__ maxes) {
  const int tid = threadIdx.x;
  if (blockIdx.x == 0 && blockIdx.y == 0 && tid == 0) {
    maxes[0] = 0u; maxes[1] = 0u;   // fold memset into K1 (K3 runs later in stream)
  }
  const int img = blockIdx.y;
  const int row = blockIdx.x * 16 + ((tid >> 6) << 2) + ((tid & 63) >> 4);
  const int l16 = tid & 15;
  const float* xr = x + (((size_t)img) << 18) + row * NN;

  float gr0 = 0.f, gr1 = 0.f, gi1 = 0.f, gr2 = 0.f, gi2 = 0.f, gr3 = 0.f, gi3 = 0.f;
  const float cd  = 0.99992470183914454f;    // cos(2pi/512)
  const float sd  = 0.012271538285719925f;   // sin(2pi/512)
  const float r45 = 0.70710678118654752f;    // cos(pi/4) = sin(pi/4), EXACT rotation/iter
  float c, s;
  __sincosf(TWOPI_N * (float)(l16 * 4), &s, &c);
  #pragma unroll
  for (int it = 0; it < 8; ++it) {
    const float4 xv = *reinterpret_cast<const float4*>(xr + it * 64 + l16 * 4);
    const float xe[4] = {xv.x, xv.y, xv.z, xv.w};
    float cc = c, ss = s;
    #pragma unroll
    for (int j = 0; j < 4; ++j) {
      const float c2 = cc * cc - ss * ss, s2 = 2.f * cc * ss;
      const float c3 = cc * c2 - ss * s2, s3 = ss * c2 + cc * s2;
      const float xx = xe[j];
      gr0 += xx;
      gr1 = fmaf(xx, cc, gr1);  gi1 = fmaf(-xx, ss, gi1);   // e^{-i*1*theta}
      gr2 = fmaf(xx, c2, gr2);  gi2 = fmaf(-xx, s2, gi2);
      gr3 = fmaf(xx, c3, gr3);  gi3 = fmaf(-xx, s3, gi3);
      const float cn = cc * cd - ss * sd;
      const float sn = ss * cd + cc * sd;
      cc = cn; ss = sn;
    }
    const float cN = r45 * (c - s);   // advance base by 64 columns = pi/4, exact
    const float sN = r45 * (c + s);
    c = cN; s = sN;
  }
  #pragma unroll
  for (int off = 8; off; off >>= 1) {
    gr0 += __shfl_down(gr0, off);
    gr1 += __shfl_down(gr1, off); gi1 += __shfl_down(gi1, off);
    gr2 += __shfl_down(gr2, off); gi2 += __shfl_down(gi2, off);
    gr3 += __shfl_down(gr3, off); gi3 += __shfl_down(gi3, off);
  }
  if (l16 == 0) {
    float* g = G + (size_t)(img * 512 + row) * 8;
    *reinterpret_cast<float4*>(g)     = make_float4(gr0, 0.f, gr1, gi1);
    *reinterpret_cast<float4*>(g + 4) = make_float4(gr2, gi2, gr3, gi3);
  }
}

// ---------------- K2: bin-parallel col-DFT -> Rtab ----------------
__global__ __launch_bounds__(512) void k2_colfft(const float* __restrict__ G,
                                                 float* __restrict__ Rtab) {
  const int img = blockIdx.x;
  const int tid = threadIdx.x;
  __shared__ float sG[512][9];          // 8 cols used + 1 pad (bank spread)
  __shared__ float parts[28][18][2];
  __shared__ float Ff[56];

  {  // stage G for this image
    const float* g = G + (size_t)img * 4096 + tid * 8;
    const float4 ga = *reinterpret_cast<const float4*>(g);
    const float4 gb = *reinterpret_cast<const float4*>(g + 4);
    sG[tid][0] = ga.x; sG[tid][1] = ga.y; sG[tid][2] = ga.z; sG[tid][3] = ga.w;
    sG[tid][4] = gb.x; sG[tid][5] = gb.y; sG[tid][6] = gb.z; sG[tid][7] = gb.w;
  }
  __syncthreads();

  if (tid < 504) {
    const int b = tid / 18;          // bin 0..27  (ky = b/7, kxs = b%7)
    const int k = tid % 18;
    const int ky = b / 7, kxs = b % 7;
    const int a = (kxs < 3) ? (3 - kxs) : (kxs - 3);
    const float sgn = (kxs < 3) ? -1.f : 1.f;   // G[u,-k] = conj(G[u,k])
    float pr = 0.f, pi = 0.f;
    for (int u = k; u < 512; u += 18) {
      const float gr = sG[u][a * 2];
      const float gi = sgn * sG[u][a * 2 + 1];  // sG[u][1] == 0 for a==0
      const int m = (ky * u) & 511;             // exact period-512 reduction
      float cc, ss;
      __sincosf(TWOPI_N * (float)m, &ss, &cc);  // e^{-i ky u th} = (cc, -ss)
      pr += gr * cc + gi * ss;
      pi += gi * cc - gr * ss;
    }
    parts[b][k][0] = pr; parts[b][k][1] = pi;
  }
  __syncthreads();
  if (tid < 28) {
    float sr = 0.f, si = 0.f;
    #pragma unroll
    for (int k = 0; k < 18; ++k) { sr += parts[tid][k][0]; si += parts[tid][k][1]; }
    Ff[2 * tid] = sr; Ff[2 * tid + 1] = si;
  }
  __syncthreads();

  // per-x table: Rtab[x][8] = (R0, 2R1r, 2R1i, 2R2r, 2R2i, 2R3r, 2R3i, 0)/N^2
  float fr[28], fi[28];
  #pragma unroll
  for (int f = 0; f < 28; ++f) { fr[f] = Ff[2 * f]; fi[f] = Ff[2 * f + 1]; }
  const int xx = tid;                 // 512 threads -> one x each
  float c1, s1;
  __sincosf(TWOPI_N * (float)xx, &s1, &c1);
  const float c2 = c1 * c1 - s1 * s1, s2 = 2.f * c1 * s1;
  const float c3 = c1 * c2 - s1 * s2, s3 = s1 * c2 + c1 * s2;
  const float pc[4] = {1.f, c1, c2, c3};
  const float ps[4] = {0.f, s1, s2, s3};
  float Rr[4], Ri[4];
  #pragma unroll
  for (int ky = 0; ky < 4; ++ky) {
    float rr = 0.f, ri = 0.f;
    #pragma unroll
    for (int kxs = 0; kxs < 7; ++kxs) {
      if (ky == 3 && (kxs == 0 || kxs == 6)) continue;  // 9+9 >= 16 excluded
      const int a = (kxs < 3) ? (3 - kxs) : (kxs - 3);
      const float ec = pc[a];
      const float es = (kxs < 3) ? -ps[a] : ps[a];      // e^{+i kx x th}
      const int f = ky * 7 + kxs;
      rr += fr[f] * ec - fi[f] * es;
      ri += fr[f] * es + fi[f] * ec;
    }
    Rr[ky] = rr; Ri[ky] = ri;
  }
  float* o = Rtab + (size_t)(img * 512 + xx) * 8;
  const float k2s = 2.f * INV_N2;
  *reinterpret_cast<float4*>(o) =
      make_float4(Rr[0] * INV_N2, Rr[1] * k2s, Ri[1] * k2s, Rr[2] * k2s);
  *reinterpret_cast<float4*>(o + 4) =
      make_float4(Ri[2] * k2s, Rr[3] * k2s, Ri[3] * k2s, 0.f);
}

// ---------------- shared per-block prologue for K3/K4 (16-row tiles) --------
__device__ __forceinline__ void load_ctx16(const float* __restrict__ Rtab, int img,
                                           int xi, int ybase, int tid,
                                           float (*yt)[6], float4 Ra[4], float4 Rb[4]) {
  if (tid < 16) {
    const int y = ybase + tid;
    float c1, s1;
    __sincosf(TWOPI_N * (float)y, &s1, &c1);
    const float c2 = c1 * c1 - s1 * s1, s2 = 2.f * c1 * s1;
    const float c3 = c1 * c2 - s1 * s2, s3 = s1 * c2 + c1 * s2;
    yt[tid][0] = c1; yt[tid][1] = s1;
    yt[tid][2] = c2; yt[tid][3] = s2;
    yt[tid][4] = c3; yt[tid][5] = s3;
  }
  const float* rt = Rtab + (size_t)(img * 512 + xi) * 8;
  #pragma unroll
  for (int j = 0; j < 4; ++j) {
    Ra[j] = *reinterpret_cast<const float4*>(rt + j * 8);
    Rb[j] = *reinterpret_cast<const float4*>(rt + j * 8 + 4);
  }
  __syncthreads();
}

__device__ __forceinline__ float recon(const float4& Ra, const float4& Rb,
                                       const float* yy) {
  float S = Ra.x;
  S = fmaf(Ra.y,  yy[0], S); S = fmaf(-Ra.z, yy[1], S);
  S = fmaf(Ra.w,  yy[2], S); S = fmaf(-Rb.x, yy[3], S);
  S = fmaf(Rb.y,  yy[4], S); S = fmaf(-Rb.z, yy[5], S);
  return S;
}

// ---------------- K3: global maxes + channel-0 x-copy (NT) ----------------
__global__ __launch_bounds__(256) void k3_maxcopy(const float* __restrict__ x,
    const float* __restrict__ Rtab, unsigned int* __restrict__ maxes,
    float* __restrict__ out) {
  const int img = blockIdx.y;
  const int b = img / 3, c = img - b * 3;
  const int tid = threadIdx.x;
  const int xi = (tid & 127) * 4;
  const int p = tid >> 7;
  const int ybase = blockIdx.x * 16;
  __shared__ float yt[16][6];
  float4 Ra[4], Rb[4];
  load_ctx16(Rtab, img, xi, ybase, tid, yt, Ra, Rb);
  const float* xim = x + (((size_t)img) << 18);
  float* o0 = out + (((size_t)(b * 9 + c)) << 18);
  float mlp = 0.f, mhp = 0.f;
  for (int it = 0; it < 8; ++it) {
    const int yy = it * 2 + p;
    const int y = ybase + yy;
    float yv[6];
    #pragma unroll
    for (int q = 0; q < 6; ++q) yv[q] = yt[yy][q];
    const float4 xv = *reinterpret_cast<const float4*>(xim + y * NN + xi);
    f4v xvv = {xv.x, xv.y, xv.z, xv.w};
    __builtin_nontemporal_store(xvv, reinterpret_cast<f4v*>(o0 + y * NN + xi));
    const float xe[4] = {xv.x, xv.y, xv.z, xv.w};
    #pragma unroll
    for (int j = 0; j < 4; ++j) {
      const float sig = recon(Ra[j], Rb[j], yv);
      mlp = fmaxf(mlp, fabsf(sig));
      mhp = fmaxf(mhp, fabsf(xe[j] - sig));
    }
  }
  #pragma unroll
  for (int off = 32; off; off >>= 1) {
    mlp = fmaxf(mlp, __shfl_down(mlp, off));
    mhp = fmaxf(mhp, __shfl_down(mhp, off));
  }
  __shared__ float sm[8];
  const int lane = tid & 63, wv = tid >> 6;
  if (lane == 0) { sm[wv * 2] = mlp; sm[wv * 2 + 1] = mhp; }
  __syncthreads();
  if (tid == 0) {
    const float a  = fmaxf(fmaxf(sm[0], sm[2]), fmaxf(sm[4], sm[6]));
    const float bb = fmaxf(fmaxf(sm[1], sm[3]), fmaxf(sm[5], sm[7]));
    atomicMax(&maxes[0], __float_as_uint(a));   // nonneg floats: bit order == value order
    atomicMax(&maxes[1], __float_as_uint(bb));
  }
}

// ---------------- K4: one channel per block (z: 0=lp, 1=hp), NT stores ------
__global__ __launch_bounds__(256) void k4_write(const float* __restrict__ x,
    const float* __restrict__ Rtab, const unsigned int* __restrict__ maxes,
    float* __restrict__ out) {
  const int img = blockIdx.y;
  const int b = img / 3, c = img - b * 3;
  const int ch = blockIdx.z;          // 0 -> lp plane, 1 -> hp plane
  const int tid = threadIdx.x;
  const int xi = (tid & 127) * 4;
  const int p = tid >> 7;
  const int ybase = blockIdx.x * 16;
  __shared__ float yt[16][6];
  float4 Ra[4], Rb[4];
  load_ctx16(Rtab, img, xi, ybase, tid, yt, Ra, Rb);
  const float inv = 1.f / __uint_as_float(maxes[ch]);
  const float* xim = x + (((size_t)img) << 18);
  float* op = out + (((size_t)(b * 9 + 3 + ch * 3 + c)) << 18);
  for (int it = 0; it < 8; ++it) {
    const int yy = it * 2 + p;
    const int y = ybase + yy;
    float yv[6];
    #pragma unroll
    for (int q = 0; q < 6; ++q) yv[q] = yt[yy][q];
    const float4 xv = *reinterpret_cast<const float4*>(xim + y * NN + xi);
    const float xe[4] = {xv.x, xv.y, xv.z, xv.w};
    f4v ov;
    #pragma unroll
    for (int j = 0; j < 4; ++j) {
      const float sig = recon(Ra[j], Rb[j], yv);
      ov[j] = (ch == 0 ? fabsf(sig) : fabsf(xe[j] - sig)) * inv;
    }
    __builtin_nontemporal_store(ov, reinterpret_cast<f4v*>(op + y * NN + xi));
  }
}

extern "C" void kernel_launch(void* const* d_in, const int* in_sizes, int n_in,
                              void* d_out, int out_size, void* d_ws, size_t ws_size,
                              hipStream_t stream) {
  if (ws_size < (size_t)WS_NEEDED) return;  // loud failure instead of corruption
  const float* x = (const float*)d_in[0];
  float* out = (float*)d_out;
  char* ws = (char*)d_ws;
  float* G = (float*)(ws + G_OFF);
  float* Rtab = (float*)(ws + R_OFF);
  unsigned int* maxes = (unsigned int*)(ws + MAX_OFF);

  k1_rowfft<<<dim3(32, IMGS), 256, 0, stream>>>(x, G, maxes);
  k2_colfft<<<dim3(IMGS), 512, 0, stream>>>(G, Rtab);
  k3_maxcopy<<<dim3(32, IMGS), 256, 0, stream>>>(x, Rtab, maxes, out);
  k4_write<<<dim3(32, IMGS, 2), 256, 0, stream>>>(x, Rtab, maxes, out);
}

// Round 9
// 135.590 us; speedup vs baseline: 2.0386x; 1.2918x over previous
//
#include <hip/hip_runtime.h>

// FeatureExtractor: out = concat([x, |ifft2(low)|/max, |ifft2(high)|/max], axis=1)
// x: (32,3,512,512) fp32. Mask keeps 45 freq bins (|ky|,|kx|<=3, ky^2+kx^2<16).
// Low-pass signal s is REAL (symmetric mask, real input); hp = |x - s|.
// Pipeline: K1 row-DFT -> K2 col-DFT + Rtab -> K3 maxes + ch0 copy -> K4 lp/hp.
// R9: R6 structure (best, 146.8us) + ONE change: explicit 4-deep load batching
// in K3/K4 inner loops (4 independent float4 loads in flight per wave; stores
// issued before dependent compute) to raise memory-level parallelism.

#define NN 512
#define IMGS 96
constexpr float TWOPI_N = 6.2831853071795864769f / 512.0f;
constexpr float INV_N2  = 1.0f / (512.0f * 512.0f);

typedef float f4v __attribute__((ext_vector_type(4)));

// workspace layout (bytes)
#define G_OFF   0                              // 96*512*8 floats = 1,572,864 B
#define R_OFF   (96 * 512 * 8 * 4)             // Rtab: 96*512*8 floats = 1,572,864 B
#define MAX_OFF (R_OFF + 96 * 512 * 8 * 4)     // 2 uints
#define WS_NEEDED (MAX_OFF + 8)

// ---------------- K1: per-row DFT at kx=0..3 (4 rows/wave, 16 lanes/row) ----
__global__ __launch_bounds__(256) void k1_rowfft(const float* __restrict__ x,
                                                 float* __restrict__ G,
                                                 unsigned int* __restrict__ maxes) {
  const int tid = threadIdx.x;
  if (blockIdx.x == 0 && blockIdx.y == 0 && tid == 0) {
    maxes[0] = 0u; maxes[1] = 0u;   // fold memset into K1 (K3 runs later in stream)
  }
  const int img = blockIdx.y;
  const int row = blockIdx.x * 16 + ((tid >> 6) << 2) + ((tid & 63) >> 4);
  const int l16 = tid & 15;
  const float* xr = x + (((size_t)img) << 18) + row * NN;

  float gr0 = 0.f, gr1 = 0.f, gi1 = 0.f, gr2 = 0.f, gi2 = 0.f, gr3 = 0.f, gi3 = 0.f;
  const float cd  = 0.99992470183914454f;    // cos(2pi/512)
  const float sd  = 0.012271538285719925f;   // sin(2pi/512)
  const float r45 = 0.70710678118654752f;    // cos(pi/4) = sin(pi/4), EXACT rotation/iter
  float c, s;
  __sincosf(TWOPI_N * (float)(l16 * 4), &s, &c);
  #pragma unroll
  for (int it = 0; it < 8; ++it) {
    const float4 xv = *reinterpret_cast<const float4*>(xr + it * 64 + l16 * 4);
    const float xe[4] = {xv.x, xv.y, xv.z, xv.w};
    float cc = c, ss = s;
    #pragma unroll
    for (int j = 0; j < 4; ++j) {
      const float c2 = cc * cc - ss * ss, s2 = 2.f * cc * ss;
      const float c3 = cc * c2 - ss * s2, s3 = ss * c2 + cc * s2;
      const float xx = xe[j];
      gr0 += xx;
      gr1 = fmaf(xx, cc, gr1);  gi1 = fmaf(-xx, ss, gi1);   // e^{-i*1*theta}
      gr2 = fmaf(xx, c2, gr2);  gi2 = fmaf(-xx, s2, gi2);
      gr3 = fmaf(xx, c3, gr3);  gi3 = fmaf(-xx, s3, gi3);
      const float cn = cc * cd - ss * sd;
      const float sn = ss * cd + cc * sd;
      cc = cn; ss = sn;
    }
    const float cN = r45 * (c - s);   // advance base by 64 columns = pi/4, exact
    const float sN = r45 * (c + s);
    c = cN; s = sN;
  }
  #pragma unroll
  for (int off = 8; off; off >>= 1) {
    gr0 += __shfl_down(gr0, off);
    gr1 += __shfl_down(gr1, off); gi1 += __shfl_down(gi1, off);
    gr2 += __shfl_down(gr2, off); gi2 += __shfl_down(gi2, off);
    gr3 += __shfl_down(gr3, off); gi3 += __shfl_down(gi3, off);
  }
  if (l16 == 0) {
    float* g = G + (size_t)(img * 512 + row) * 8;
    *reinterpret_cast<float4*>(g)     = make_float4(gr0, 0.f, gr1, gi1);
    *reinterpret_cast<float4*>(g + 4) = make_float4(gr2, gi2, gr3, gi3);
  }
}

// ---------------- K2: bin-parallel col-DFT -> Rtab ----------------
__global__ __launch_bounds__(512) void k2_colfft(const float* __restrict__ G,
                                                 float* __restrict__ Rtab) {
  const int img = blockIdx.x;
  const int tid = threadIdx.x;
  __shared__ float sG[512][9];          // 8 cols used + 1 pad (bank spread)
  __shared__ float parts[28][18][2];
  __shared__ float Ff[56];

  {  // stage G for this image
    const float* g = G + (size_t)img * 4096 + tid * 8;
    const float4 ga = *reinterpret_cast<const float4*>(g);
    const float4 gb = *reinterpret_cast<const float4*>(g + 4);
    sG[tid][0] = ga.x; sG[tid][1] = ga.y; sG[tid][2] = ga.z; sG[tid][3] = ga.w;
    sG[tid][4] = gb.x; sG[tid][5] = gb.y; sG[tid][6] = gb.z; sG[tid][7] = gb.w;
  }
  __syncthreads();

  if (tid < 504) {
    const int b = tid / 18;          // bin 0..27  (ky = b/7, kxs = b%7)
    const int k = tid % 18;
    const int ky = b / 7, kxs = b % 7;
    const int a = (kxs < 3) ? (3 - kxs) : (kxs - 3);
    const float sgn = (kxs < 3) ? -1.f : 1.f;   // G[u,-k] = conj(G[u,k])
    float pr = 0.f, pi = 0.f;
    for (int u = k; u < 512; u += 18) {
      const float gr = sG[u][a * 2];
      const float gi = sgn * sG[u][a * 2 + 1];  // sG[u][1] == 0 for a==0
      const int m = (ky * u) & 511;             // exact period-512 reduction
      float cc, ss;
      __sincosf(TWOPI_N * (float)m, &ss, &cc);  // e^{-i ky u th} = (cc, -ss)
      pr += gr * cc + gi * ss;
      pi += gi * cc - gr * ss;
    }
    parts[b][k][0] = pr; parts[b][k][1] = pi;
  }
  __syncthreads();
  if (tid < 28) {
    float sr = 0.f, si = 0.f;
    #pragma unroll
    for (int k = 0; k < 18; ++k) { sr += parts[tid][k][0]; si += parts[tid][k][1]; }
    Ff[2 * tid] = sr; Ff[2 * tid + 1] = si;
  }
  __syncthreads();

  // per-x table: Rtab[x][8] = (R0, 2R1r, 2R1i, 2R2r, 2R2i, 2R3r, 2R3i, 0)/N^2
  float fr[28], fi[28];
  #pragma unroll
  for (int f = 0; f < 28; ++f) { fr[f] = Ff[2 * f]; fi[f] = Ff[2 * f + 1]; }
  const int xx = tid;                 // 512 threads -> one x each
  float c1, s1;
  __sincosf(TWOPI_N * (float)xx, &s1, &c1);
  const float c2 = c1 * c1 - s1 * s1, s2 = 2.f * c1 * s1;
  const float c3 = c1 * c2 - s1 * s2, s3 = s1 * c2 + c1 * s2;
  const float pc[4] = {1.f, c1, c2, c3};
  const float ps[4] = {0.f, s1, s2, s3};
  float Rr[4], Ri[4];
  #pragma unroll
  for (int ky = 0; ky < 4; ++ky) {
    float rr = 0.f, ri = 0.f;
    #pragma unroll
    for (int kxs = 0; kxs < 7; ++kxs) {
      if (ky == 3 && (kxs == 0 || kxs == 6)) continue;  // 9+9 >= 16 excluded
      const int a = (kxs < 3) ? (3 - kxs) : (kxs - 3);
      const float ec = pc[a];
      const float es = (kxs < 3) ? -ps[a] : ps[a];      // e^{+i kx x th}
      const int f = ky * 7 + kxs;
      rr += fr[f] * ec - fi[f] * es;
      ri += fr[f] * es + fi[f] * ec;
    }
    Rr[ky] = rr; Ri[ky] = ri;
  }
  float* o = Rtab + (size_t)(img * 512 + xx) * 8;
  const float k2s = 2.f * INV_N2;
  *reinterpret_cast<float4*>(o) =
      make_float4(Rr[0] * INV_N2, Rr[1] * k2s, Ri[1] * k2s, Rr[2] * k2s);
  *reinterpret_cast<float4*>(o + 4) =
      make_float4(Ri[2] * k2s, Rr[3] * k2s, Ri[3] * k2s, 0.f);
}

// ---------------- shared per-block prologue for K3/K4 (32-row tiles) --------
__device__ __forceinline__ void load_ctx(const float* __restrict__ Rtab, int img,
                                         int xi, int ybase, int tid,
                                         float (*yt)[6], float4 Ra[4], float4 Rb[4]) {
  if (tid < 32) {
    const int y = ybase + tid;
    float c1, s1;
    __sincosf(TWOPI_N * (float)y, &s1, &c1);
    const float c2 = c1 * c1 - s1 * s1, s2 = 2.f * c1 * s1;
    const float c3 = c1 * c2 - s1 * s2, s3 = s1 * c2 + c1 * s2;
    yt[tid][0] = c1; yt[tid][1] = s1;
    yt[tid][2] = c2; yt[tid][3] = s2;
    yt[tid][4] = c3; yt[tid][5] = s3;
  }
  const float* rt = Rtab + (size_t)(img * 512 + xi) * 8;
  #pragma unroll
  for (int j = 0; j < 4; ++j) {
    Ra[j] = *reinterpret_cast<const float4*>(rt + j * 8);
    Rb[j] = *reinterpret_cast<const float4*>(rt + j * 8 + 4);
  }
  __syncthreads();
}

__device__ __forceinline__ float recon(const float4& Ra, const float4& Rb,
                                       const float* yy) {
  float S = Ra.x;
  S = fmaf(Ra.y,  yy[0], S); S = fmaf(-Ra.z, yy[1], S);
  S = fmaf(Ra.w,  yy[2], S); S = fmaf(-Rb.x, yy[3], S);
  S = fmaf(Rb.y,  yy[4], S); S = fmaf(-Rb.z, yy[5], S);
  return S;
}

// ---------------- K3: global maxes + channel-0 x-copy (4-deep batches) ------
__global__ __launch_bounds__(256) void k3_maxcopy(const float* __restrict__ x,
    const float* __restrict__ Rtab, unsigned int* __restrict__ maxes,
    float* __restrict__ out) {
  const int img = blockIdx.y;
  const int b = img / 3, c = img - b * 3;
  const int tid = threadIdx.x;
  const int xi = (tid & 127) * 4;
  const int p = tid >> 7;
  const int ybase = blockIdx.x * 32;
  __shared__ float yt[32][6];
  float4 Ra[4], Rb[4];
  load_ctx(Rtab, img, xi, ybase, tid, yt, Ra, Rb);
  const float* xim = x + (((size_t)img) << 18);
  float* o0 = out + (((size_t)(b * 9 + c)) << 18);
  float mlp = 0.f, mhp = 0.f;
  for (int g = 0; g < 4; ++g) {
    // batch: 4 independent loads in flight
    float4 xv[4];
    int yy[4];
    #pragma unroll
    for (int u = 0; u < 4; ++u) {
      yy[u] = (g * 4 + u) * 2 + p;
      xv[u] = *reinterpret_cast<const float4*>(xim + (ybase + yy[u]) * NN + xi);
    }
    // stores issued before dependent compute
    #pragma unroll
    for (int u = 0; u < 4; ++u) {
      *reinterpret_cast<float4*>(o0 + (ybase + yy[u]) * NN + xi) = xv[u];
    }
    #pragma unroll
    for (int u = 0; u < 4; ++u) {
      float yv[6];
      #pragma unroll
      for (int q = 0; q < 6; ++q) yv[q] = yt[yy[u]][q];
      const float xe[4] = {xv[u].x, xv[u].y, xv[u].z, xv[u].w};
      #pragma unroll
      for (int j = 0; j < 4; ++j) {
        const float sig = recon(Ra[j], Rb[j], yv);
        mlp = fmaxf(mlp, fabsf(sig));
        mhp = fmaxf(mhp, fabsf(xe[j] - sig));
      }
    }
  }
  #pragma unroll
  for (int off = 32; off; off >>= 1) {
    mlp = fmaxf(mlp, __shfl_down(mlp, off));
    mhp = fmaxf(mhp, __shfl_down(mhp, off));
  }
  __shared__ float sm[8];
  const int lane = tid & 63, wv = tid >> 6;
  if (lane == 0) { sm[wv * 2] = mlp; sm[wv * 2 + 1] = mhp; }
  __syncthreads();
  if (tid == 0) {
    const float a  = fmaxf(fmaxf(sm[0], sm[2]), fmaxf(sm[4], sm[6]));
    const float bb = fmaxf(fmaxf(sm[1], sm[3]), fmaxf(sm[5], sm[7]));
    atomicMax(&maxes[0], __float_as_uint(a));   // nonneg floats: bit order == value order
    atomicMax(&maxes[1], __float_as_uint(bb));
  }
}

// ---------------- K4: lp/hp write (4-deep batches) ----------------
__global__ __launch_bounds__(256) void k4_write(const float* __restrict__ x,
    const float* __restrict__ Rtab, const unsigned int* __restrict__ maxes,
    float* __restrict__ out) {
  const int img = blockIdx.y;
  const int b = img / 3, c = img - b * 3;
  const int tid = threadIdx.x;
  const int xi = (tid & 127) * 4;
  const int p = tid >> 7;
  const int ybase = blockIdx.x * 32;
  __shared__ float yt[32][6];
  float4 Ra[4], Rb[4];
  load_ctx(Rtab, img, xi, ybase, tid, yt, Ra, Rb);
  const float inv_lp = 1.f / __uint_as_float(maxes[0]);
  const float inv_hp = 1.f / __uint_as_float(maxes[1]);
  const float* xim = x + (((size_t)img) << 18);
  float* o1 = out + (((size_t)(b * 9 + 3 + c)) << 18);
  float* o2 = out + (((size_t)(b * 9 + 6 + c)) << 18);
  for (int g = 0; g < 4; ++g) {
    // batch: 4 independent loads in flight
    float4 xv[4];
    int yy[4];
    #pragma unroll
    for (int u = 0; u < 4; ++u) {
      yy[u] = (g * 4 + u) * 2 + p;
      xv[u] = *reinterpret_cast<const float4*>(xim + (ybase + yy[u]) * NN + xi);
    }
    #pragma unroll
    for (int u = 0; u < 4; ++u) {
      float yv[6];
      #pragma unroll
      for (int q = 0; q < 6; ++q) yv[q] = yt[yy[u]][q];
      const float xe[4] = {xv[u].x, xv[u].y, xv[u].z, xv[u].w};
      f4v lpv, hpv;
      #pragma unroll
      for (int j = 0; j < 4; ++j) {
        const float sig = recon(Ra[j], Rb[j], yv);
        lpv[j] = fabsf(sig) * inv_lp;
        hpv[j] = fabsf(xe[j] - sig) * inv_hp;
      }
      const int o = (ybase + yy[u]) * NN + xi;
      *reinterpret_cast<f4v*>(o1 + o) = lpv;
      *reinterpret_cast<f4v*>(o2 + o) = hpv;
    }
  }
}

extern "C" void kernel_launch(void* const* d_in, const int* in_sizes, int n_in,
                              void* d_out, int out_size, void* d_ws, size_t ws_size,
                              hipStream_t stream) {
  if (ws_size < (size_t)WS_NEEDED) return;  // loud failure instead of corruption
  const float* x = (const float*)d_in[0];
  float* out = (float*)d_out;
  char* ws = (char*)d_ws;
  float* G = (float*)(ws + G_OFF);
  float* Rtab = (float*)(ws + R_OFF);
  unsigned int* maxes = (unsigned int*)(ws + MAX_OFF);

  k1_rowfft<<<dim3(32, IMGS), 256, 0, stream>>>(x, G, maxes);
  k2_colfft<<<dim3(IMGS), 512, 0, stream>>>(G, Rtab);
  k3_maxcopy<<<dim3(16, IMGS), 256, 0, stream>>>(x, Rtab, maxes, out);
  k4_write<<<dim3(16, IMGS), 256, 0, stream>>>(x, Rtab, maxes, out);
}

// Round 10
// 131.616 us; speedup vs baseline: 2.1002x; 1.0302x over previous
//
#include <hip/hip_runtime.h>

// FeatureExtractor: out = concat([x, |ifft2(low)|/max, |ifft2(high)|/max], axis=1)
// x: (32,3,512,512) fp32. Mask keeps 45 freq bins (|ky|,|kx|<=3, ky^2+kx^2<16).
// Low-pass signal s is REAL (symmetric mask, real input); hp = |x - s|.
// Pipeline: K1 row-DFT -> K2 col-DFT + Rtab -> K3 maxes + ch0 copy -> K4 lp/hp.
// R10: R9 + ONE change: batch depth 4 -> 8 in K3/K4 (8 independent float4
// loads in flight per wave; ~100 VGPR, under the 128 occupancy cliff).

#define NN 512
#define IMGS 96
constexpr float TWOPI_N = 6.2831853071795864769f / 512.0f;
constexpr float INV_N2  = 1.0f / (512.0f * 512.0f);

typedef float f4v __attribute__((ext_vector_type(4)));

// workspace layout (bytes)
#define G_OFF   0                              // 96*512*8 floats = 1,572,864 B
#define R_OFF   (96 * 512 * 8 * 4)             // Rtab: 96*512*8 floats = 1,572,864 B
#define MAX_OFF (R_OFF + 96 * 512 * 8 * 4)     // 2 uints
#define WS_NEEDED (MAX_OFF + 8)

// ---------------- K1: per-row DFT at kx=0..3 (4 rows/wave, 16 lanes/row) ----
__global__ __launch_bounds__(256) void k1_rowfft(const float* __restrict__ x,
                                                 float* __restrict__ G,
                                                 unsigned int* __restrict__ maxes) {
  const int tid = threadIdx.x;
  if (blockIdx.x == 0 && blockIdx.y == 0 && tid == 0) {
    maxes[0] = 0u; maxes[1] = 0u;   // fold memset into K1 (K3 runs later in stream)
  }
  const int img = blockIdx.y;
  const int row = blockIdx.x * 16 + ((tid >> 6) << 2) + ((tid & 63) >> 4);
  const int l16 = tid & 15;
  const float* xr = x + (((size_t)img) << 18) + row * NN;

  float gr0 = 0.f, gr1 = 0.f, gi1 = 0.f, gr2 = 0.f, gi2 = 0.f, gr3 = 0.f, gi3 = 0.f;
  const float cd  = 0.99992470183914454f;    // cos(2pi/512)
  const float sd  = 0.012271538285719925f;   // sin(2pi/512)
  const float r45 = 0.70710678118654752f;    // cos(pi/4) = sin(pi/4), EXACT rotation/iter
  float c, s;
  __sincosf(TWOPI_N * (float)(l16 * 4), &s, &c);
  #pragma unroll
  for (int it = 0; it < 8; ++it) {
    const float4 xv = *reinterpret_cast<const float4*>(xr + it * 64 + l16 * 4);
    const float xe[4] = {xv.x, xv.y, xv.z, xv.w};
    float cc = c, ss = s;
    #pragma unroll
    for (int j = 0; j < 4; ++j) {
      const float c2 = cc * cc - ss * ss, s2 = 2.f * cc * ss;
      const float c3 = cc * c2 - ss * s2, s3 = ss * c2 + cc * s2;
      const float xx = xe[j];
      gr0 += xx;
      gr1 = fmaf(xx, cc, gr1);  gi1 = fmaf(-xx, ss, gi1);   // e^{-i*1*theta}
      gr2 = fmaf(xx, c2, gr2);  gi2 = fmaf(-xx, s2, gi2);
      gr3 = fmaf(xx, c3, gr3);  gi3 = fmaf(-xx, s3, gi3);
      const float cn = cc * cd - ss * sd;
      const float sn = ss * cd + cc * sd;
      cc = cn; ss = sn;
    }
    const float cN = r45 * (c - s);   // advance base by 64 columns = pi/4, exact
    const float sN = r45 * (c + s);
    c = cN; s = sN;
  }
  #pragma unroll
  for (int off = 8; off; off >>= 1) {
    gr0 += __shfl_down(gr0, off);
    gr1 += __shfl_down(gr1, off); gi1 += __shfl_down(gi1, off);
    gr2 += __shfl_down(gr2, off); gi2 += __shfl_down(gi2, off);
    gr3 += __shfl_down(gr3, off); gi3 += __shfl_down(gi3, off);
  }
  if (l16 == 0) {
    float* g = G + (size_t)(img * 512 + row) * 8;
    *reinterpret_cast<float4*>(g)     = make_float4(gr0, 0.f, gr1, gi1);
    *reinterpret_cast<float4*>(g + 4) = make_float4(gr2, gi2, gr3, gi3);
  }
}

// ---------------- K2: bin-parallel col-DFT -> Rtab ----------------
__global__ __launch_bounds__(512) void k2_colfft(const float* __restrict__ G,
                                                 float* __restrict__ Rtab) {
  const int img = blockIdx.x;
  const int tid = threadIdx.x;
  __shared__ float sG[512][9];          // 8 cols used + 1 pad (bank spread)
  __shared__ float parts[28][18][2];
  __shared__ float Ff[56];

  {  // stage G for this image
    const float* g = G + (size_t)img * 4096 + tid * 8;
    const float4 ga = *reinterpret_cast<const float4*>(g);
    const float4 gb = *reinterpret_cast<const float4*>(g + 4);
    sG[tid][0] = ga.x; sG[tid][1] = ga.y; sG[tid][2] = ga.z; sG[tid][3] = ga.w;
    sG[tid][4] = gb.x; sG[tid][5] = gb.y; sG[tid][6] = gb.z; sG[tid][7] = gb.w;
  }
  __syncthreads();

  if (tid < 504) {
    const int b = tid / 18;          // bin 0..27  (ky = b/7, kxs = b%7)
    const int k = tid % 18;
    const int ky = b / 7, kxs = b % 7;
    const int a = (kxs < 3) ? (3 - kxs) : (kxs - 3);
    const float sgn = (kxs < 3) ? -1.f : 1.f;   // G[u,-k] = conj(G[u,k])
    float pr = 0.f, pi = 0.f;
    for (int u = k; u < 512; u += 18) {
      const float gr = sG[u][a * 2];
      const float gi = sgn * sG[u][a * 2 + 1];  // sG[u][1] == 0 for a==0
      const int m = (ky * u) & 511;             // exact period-512 reduction
      float cc, ss;
      __sincosf(TWOPI_N * (float)m, &ss, &cc);  // e^{-i ky u th} = (cc, -ss)
      pr += gr * cc + gi * ss;
      pi += gi * cc - gr * ss;
    }
    parts[b][k][0] = pr; parts[b][k][1] = pi;
  }
  __syncthreads();
  if (tid < 28) {
    float sr = 0.f, si = 0.f;
    #pragma unroll
    for (int k = 0; k < 18; ++k) { sr += parts[tid][k][0]; si += parts[tid][k][1]; }
    Ff[2 * tid] = sr; Ff[2 * tid + 1] = si;
  }
  __syncthreads();

  // per-x table: Rtab[x][8] = (R0, 2R1r, 2R1i, 2R2r, 2R2i, 2R3r, 2R3i, 0)/N^2
  float fr[28], fi[28];
  #pragma unroll
  for (int f = 0; f < 28; ++f) { fr[f] = Ff[2 * f]; fi[f] = Ff[2 * f + 1]; }
  const int xx = tid;                 // 512 threads -> one x each
  float c1, s1;
  __sincosf(TWOPI_N * (float)xx, &s1, &c1);
  const float c2 = c1 * c1 - s1 * s1, s2 = 2.f * c1 * s1;
  const float c3 = c1 * c2 - s1 * s2, s3 = s1 * c2 + c1 * s2;
  const float pc[4] = {1.f, c1, c2, c3};
  const float ps[4] = {0.f, s1, s2, s3};
  float Rr[4], Ri[4];
  #pragma unroll
  for (int ky = 0; ky < 4; ++ky) {
    float rr = 0.f, ri = 0.f;
    #pragma unroll
    for (int kxs = 0; kxs < 7; ++kxs) {
      if (ky == 3 && (kxs == 0 || kxs == 6)) continue;  // 9+9 >= 16 excluded
      const int a = (kxs < 3) ? (3 - kxs) : (kxs - 3);
      const float ec = pc[a];
      const float es = (kxs < 3) ? -ps[a] : ps[a];      // e^{+i kx x th}
      const int f = ky * 7 + kxs;
      rr += fr[f] * ec - fi[f] * es;
      ri += fr[f] * es + fi[f] * ec;
    }
    Rr[ky] = rr; Ri[ky] = ri;
  }
  float* o = Rtab + (size_t)(img * 512 + xx) * 8;
  const float k2s = 2.f * INV_N2;
  *reinterpret_cast<float4*>(o) =
      make_float4(Rr[0] * INV_N2, Rr[1] * k2s, Ri[1] * k2s, Rr[2] * k2s);
  *reinterpret_cast<float4*>(o + 4) =
      make_float4(Ri[2] * k2s, Rr[3] * k2s, Ri[3] * k2s, 0.f);
}

// ---------------- shared per-block prologue for K3/K4 (32-row tiles) --------
__device__ __forceinline__ void load_ctx(const float* __restrict__ Rtab, int img,
                                         int xi, int ybase, int tid,
                                         float (*yt)[6], float4 Ra[4], float4 Rb[4]) {
  if (tid < 32) {
    const int y = ybase + tid;
    float c1, s1;
    __sincosf(TWOPI_N * (float)y, &s1, &c1);
    const float c2 = c1 * c1 - s1 * s1, s2 = 2.f * c1 * s1;
    const float c3 = c1 * c2 - s1 * s2, s3 = s1 * c2 + c1 * s2;
    yt[tid][0] = c1; yt[tid][1] = s1;
    yt[tid][2] = c2; yt[tid][3] = s2;
    yt[tid][4] = c3; yt[tid][5] = s3;
  }
  const float* rt = Rtab + (size_t)(img * 512 + xi) * 8;
  #pragma unroll
  for (int j = 0; j < 4; ++j) {
    Ra[j] = *reinterpret_cast<const float4*>(rt + j * 8);
    Rb[j] = *reinterpret_cast<const float4*>(rt + j * 8 + 4);
  }
  __syncthreads();
}

__device__ __forceinline__ float recon(const float4& Ra, const float4& Rb,
                                       const float* yy) {
  float S = Ra.x;
  S = fmaf(Ra.y,  yy[0], S); S = fmaf(-Ra.z, yy[1], S);
  S = fmaf(Ra.w,  yy[2], S); S = fmaf(-Rb.x, yy[3], S);
  S = fmaf(Rb.y,  yy[4], S); S = fmaf(-Rb.z, yy[5], S);
  return S;
}

// ---------------- K3: global maxes + channel-0 x-copy (8-deep batches) ------
__global__ __launch_bounds__(256) void k3_maxcopy(const float* __restrict__ x,
    const float* __restrict__ Rtab, unsigned int* __restrict__ maxes,
    float* __restrict__ out) {
  const int img = blockIdx.y;
  const int b = img / 3, c = img - b * 3;
  const int tid = threadIdx.x;
  const int xi = (tid & 127) * 4;
  const int p = tid >> 7;
  const int ybase = blockIdx.x * 32;
  __shared__ float yt[32][6];
  float4 Ra[4], Rb[4];
  load_ctx(Rtab, img, xi, ybase, tid, yt, Ra, Rb);
  const float* xim = x + (((size_t)img) << 18);
  float* o0 = out + (((size_t)(b * 9 + c)) << 18);
  float mlp = 0.f, mhp = 0.f;
  for (int g = 0; g < 2; ++g) {
    // batch: 8 independent loads in flight
    float4 xv[8];
    int yy[8];
    #pragma unroll
    for (int u = 0; u < 8; ++u) {
      yy[u] = (g * 8 + u) * 2 + p;
      xv[u] = *reinterpret_cast<const float4*>(xim + (ybase + yy[u]) * NN + xi);
    }
    // stores issued before dependent compute
    #pragma unroll
    for (int u = 0; u < 8; ++u) {
      *reinterpret_cast<float4*>(o0 + (ybase + yy[u]) * NN + xi) = xv[u];
    }
    #pragma unroll
    for (int u = 0; u < 8; ++u) {
      float yv[6];
      #pragma unroll
      for (int q = 0; q < 6; ++q) yv[q] = yt[yy[u]][q];
      const float xe[4] = {xv[u].x, xv[u].y, xv[u].z, xv[u].w};
      #pragma unroll
      for (int j = 0; j < 4; ++j) {
        const float sig = recon(Ra[j], Rb[j], yv);
        mlp = fmaxf(mlp, fabsf(sig));
        mhp = fmaxf(mhp, fabsf(xe[j] - sig));
      }
    }
  }
  #pragma unroll
  for (int off = 32; off; off >>= 1) {
    mlp = fmaxf(mlp, __shfl_down(mlp, off));
    mhp = fmaxf(mhp, __shfl_down(mhp, off));
  }
  __shared__ float sm[8];
  const int lane = tid & 63, wv = tid >> 6;
  if (lane == 0) { sm[wv * 2] = mlp; sm[wv * 2 + 1] = mhp; }
  __syncthreads();
  if (tid == 0) {
    const float a  = fmaxf(fmaxf(sm[0], sm[2]), fmaxf(sm[4], sm[6]));
    const float bb = fmaxf(fmaxf(sm[1], sm[3]), fmaxf(sm[5], sm[7]));
    atomicMax(&maxes[0], __float_as_uint(a));   // nonneg floats: bit order == value order
    atomicMax(&maxes[1], __float_as_uint(bb));
  }
}

// ---------------- K4: lp/hp write (8-deep batches) ----------------
__global__ __launch_bounds__(256) void k4_write(const float* __restrict__ x,
    const float* __restrict__ Rtab, const unsigned int* __restrict__ maxes,
    float* __restrict__ out) {
  const int img = blockIdx.y;
  const int b = img / 3, c = img - b * 3;
  const int tid = threadIdx.x;
  const int xi = (tid & 127) * 4;
  const int p = tid >> 7;
  const int ybase = blockIdx.x * 32;
  __shared__ float yt[32][6];
  float4 Ra[4], Rb[4];
  load_ctx(Rtab, img, xi, ybase, tid, yt, Ra, Rb);
  const float inv_lp = 1.f / __uint_as_float(maxes[0]);
  const float inv_hp = 1.f / __uint_as_float(maxes[1]);
  const float* xim = x + (((size_t)img) << 18);
  float* o1 = out + (((size_t)(b * 9 + 3 + c)) << 18);
  float* o2 = out + (((size_t)(b * 9 + 6 + c)) << 18);
  for (int g = 0; g < 2; ++g) {
    // batch: 8 independent loads in flight
    float4 xv[8];
    int yy[8];
    #pragma unroll
    for (int u = 0; u < 8; ++u) {
      yy[u] = (g * 8 + u) * 2 + p;
      xv[u] = *reinterpret_cast<const float4*>(xim + (ybase + yy[u]) * NN + xi);
    }
    #pragma unroll
    for (int u = 0; u < 8; ++u) {
      float yv[6];
      #pragma unroll
      for (int q = 0; q < 6; ++q) yv[q] = yt[yy[u]][q];
      const float xe[4] = {xv[u].x, xv[u].y, xv[u].z, xv[u].w};
      f4v lpv, hpv;
      #pragma unroll
      for (int j = 0; j < 4; ++j) {
        const float sig = recon(Ra[j], Rb[j], yv);
        lpv[j] = fabsf(sig) * inv_lp;
        hpv[j] = fabsf(xe[j] - sig) * inv_hp;
      }
      const int o = (ybase + yy[u]) * NN + xi;
      *reinterpret_cast<f4v*>(o1 + o) = lpv;
      *reinterpret_cast<f4v*>(o2 + o) = hpv;
    }
  }
}

extern "C" void kernel_launch(void* const* d_in, const int* in_sizes, int n_in,
                              void* d_out, int out_size, void* d_ws, size_t ws_size,
                              hipStream_t stream) {
  if (ws_size < (size_t)WS_NEEDED) return;  // loud failure instead of corruption
  const float* x = (const float*)d_in[0];
  float* out = (float*)d_out;
  char* ws = (char*)d_ws;
  float* G = (float*)(ws + G_OFF);
  float* Rtab = (float*)(ws + R_OFF);
  unsigned int* maxes = (unsigned int*)(ws + MAX_OFF);

  k1_rowfft<<<dim3(32, IMGS), 256, 0, stream>>>(x, G, maxes);
  k2_colfft<<<dim3(IMGS), 512, 0, stream>>>(G, Rtab);
  k3_maxcopy<<<dim3(16, IMGS), 256, 0, stream>>>(x, Rtab, maxes, out);
  k4_write<<<dim3(16, IMGS), 256, 0, stream>>>(x, Rtab, maxes, out);
}

// Round 11
// 124.998 us; speedup vs baseline: 2.2113x; 1.0529x over previous
//
#include <hip/hip_runtime.h>

// FeatureExtractor: out = concat([x, |ifft2(low)|/max, |ifft2(high)|/max], axis=1)
// x: (32,3,512,512) fp32. Mask keeps 45 freq bins (|ky|,|kx|<=3, ky^2+kx^2<16).
// Low-pass signal s is REAL (symmetric mask, real input); hp = |x - s|.
// Pipeline: K1 row-DFT -> K2 col-DFT + Rtab -> K3 maxes + ch0 copy -> K4 lp/hp.
// R11: R10 + ONE change: non-temporal stores for ALL output writes (output is
// never re-read; keeps x L3-resident so K3/K4 x re-reads stay L3-hits).

#define NN 512
#define IMGS 96
constexpr float TWOPI_N = 6.2831853071795864769f / 512.0f;
constexpr float INV_N2  = 1.0f / (512.0f * 512.0f);

typedef float f4v __attribute__((ext_vector_type(4)));

// workspace layout (bytes)
#define G_OFF   0                              // 96*512*8 floats = 1,572,864 B
#define R_OFF   (96 * 512 * 8 * 4)             // Rtab: 96*512*8 floats = 1,572,864 B
#define MAX_OFF (R_OFF + 96 * 512 * 8 * 4)     // 2 uints
#define WS_NEEDED (MAX_OFF + 8)

// ---------------- K1: per-row DFT at kx=0..3 (4 rows/wave, 16 lanes/row) ----
__global__ __launch_bounds__(256) void k1_rowfft(const float* __restrict__ x,
                                                 float* __restrict__ G,
                                                 unsigned int* __restrict__ maxes) {
  const int tid = threadIdx.x;
  if (blockIdx.x == 0 && blockIdx.y == 0 && tid == 0) {
    maxes[0] = 0u; maxes[1] = 0u;   // fold memset into K1 (K3 runs later in stream)
  }
  const int img = blockIdx.y;
  const int row = blockIdx.x * 16 + ((tid >> 6) << 2) + ((tid & 63) >> 4);
  const int l16 = tid & 15;
  const float* xr = x + (((size_t)img) << 18) + row * NN;

  float gr0 = 0.f, gr1 = 0.f, gi1 = 0.f, gr2 = 0.f, gi2 = 0.f, gr3 = 0.f, gi3 = 0.f;
  const float cd  = 0.99992470183914454f;    // cos(2pi/512)
  const float sd  = 0.012271538285719925f;   // sin(2pi/512)
  const float r45 = 0.70710678118654752f;    // cos(pi/4) = sin(pi/4), EXACT rotation/iter
  float c, s;
  __sincosf(TWOPI_N * (float)(l16 * 4), &s, &c);
  #pragma unroll
  for (int it = 0; it < 8; ++it) {
    const float4 xv = *reinterpret_cast<const float4*>(xr + it * 64 + l16 * 4);
    const float xe[4] = {xv.x, xv.y, xv.z, xv.w};
    float cc = c, ss = s;
    #pragma unroll
    for (int j = 0; j < 4; ++j) {
      const float c2 = cc * cc - ss * ss, s2 = 2.f * cc * ss;
      const float c3 = cc * c2 - ss * s2, s3 = ss * c2 + cc * s2;
      const float xx = xe[j];
      gr0 += xx;
      gr1 = fmaf(xx, cc, gr1);  gi1 = fmaf(-xx, ss, gi1);   // e^{-i*1*theta}
      gr2 = fmaf(xx, c2, gr2);  gi2 = fmaf(-xx, s2, gi2);
      gr3 = fmaf(xx, c3, gr3);  gi3 = fmaf(-xx, s3, gi3);
      const float cn = cc * cd - ss * sd;
      const float sn = ss * cd + cc * sd;
      cc = cn; ss = sn;
    }
    const float cN = r45 * (c - s);   // advance base by 64 columns = pi/4, exact
    const float sN = r45 * (c + s);
    c = cN; s = sN;
  }
  #pragma unroll
  for (int off = 8; off; off >>= 1) {
    gr0 += __shfl_down(gr0, off);
    gr1 += __shfl_down(gr1, off); gi1 += __shfl_down(gi1, off);
    gr2 += __shfl_down(gr2, off); gi2 += __shfl_down(gi2, off);
    gr3 += __shfl_down(gr3, off); gi3 += __shfl_down(gi3, off);
  }
  if (l16 == 0) {
    float* g = G + (size_t)(img * 512 + row) * 8;
    *reinterpret_cast<float4*>(g)     = make_float4(gr0, 0.f, gr1, gi1);
    *reinterpret_cast<float4*>(g + 4) = make_float4(gr2, gi2, gr3, gi3);
  }
}

// ---------------- K2: bin-parallel col-DFT -> Rtab ----------------
__global__ __launch_bounds__(512) void k2_colfft(const float* __restrict__ G,
                                                 float* __restrict__ Rtab) {
  const int img = blockIdx.x;
  const int tid = threadIdx.x;
  __shared__ float sG[512][9];          // 8 cols used + 1 pad (bank spread)
  __shared__ float parts[28][18][2];
  __shared__ float Ff[56];

  {  // stage G for this image
    const float* g = G + (size_t)img * 4096 + tid * 8;
    const float4 ga = *reinterpret_cast<const float4*>(g);
    const float4 gb = *reinterpret_cast<const float4*>(g + 4);
    sG[tid][0] = ga.x; sG[tid][1] = ga.y; sG[tid][2] = ga.z; sG[tid][3] = ga.w;
    sG[tid][4] = gb.x; sG[tid][5] = gb.y; sG[tid][6] = gb.z; sG[tid][7] = gb.w;
  }
  __syncthreads();

  if (tid < 504) {
    const int b = tid / 18;          // bin 0..27  (ky = b/7, kxs = b%7)
    const int k = tid % 18;
    const int ky = b / 7, kxs = b % 7;
    const int a = (kxs < 3) ? (3 - kxs) : (kxs - 3);
    const float sgn = (kxs < 3) ? -1.f : 1.f;   // G[u,-k] = conj(G[u,k])
    float pr = 0.f, pi = 0.f;
    for (int u = k; u < 512; u += 18) {
      const float gr = sG[u][a * 2];
      const float gi = sgn * sG[u][a * 2 + 1];  // sG[u][1] == 0 for a==0
      const int m = (ky * u) & 511;             // exact period-512 reduction
      float cc, ss;
      __sincosf(TWOPI_N * (float)m, &ss, &cc);  // e^{-i ky u th} = (cc, -ss)
      pr += gr * cc + gi * ss;
      pi += gi * cc - gr * ss;
    }
    parts[b][k][0] = pr; parts[b][k][1] = pi;
  }
  __syncthreads();
  if (tid < 28) {
    float sr = 0.f, si = 0.f;
    #pragma unroll
    for (int k = 0; k < 18; ++k) { sr += parts[tid][k][0]; si += parts[tid][k][1]; }
    Ff[2 * tid] = sr; Ff[2 * tid + 1] = si;
  }
  __syncthreads();

  // per-x table: Rtab[x][8] = (R0, 2R1r, 2R1i, 2R2r, 2R2i, 2R3r, 2R3i, 0)/N^2
  float fr[28], fi[28];
  #pragma unroll
  for (int f = 0; f < 28; ++f) { fr[f] = Ff[2 * f]; fi[f] = Ff[2 * f + 1]; }
  const int xx = tid;                 // 512 threads -> one x each
  float c1, s1;
  __sincosf(TWOPI_N * (float)xx, &s1, &c1);
  const float c2 = c1 * c1 - s1 * s1, s2 = 2.f * c1 * s1;
  const float c3 = c1 * c2 - s1 * s2, s3 = s1 * c2 + c1 * s2;
  const float pc[4] = {1.f, c1, c2, c3};
  const float ps[4] = {0.f, s1, s2, s3};
  float Rr[4], Ri[4];
  #pragma unroll
  for (int ky = 0; ky < 4; ++ky) {
    float rr = 0.f, ri = 0.f;
    #pragma unroll
    for (int kxs = 0; kxs < 7; ++kxs) {
      if (ky == 3 && (kxs == 0 || kxs == 6)) continue;  // 9+9 >= 16 excluded
      const int a = (kxs < 3) ? (3 - kxs) : (kxs - 3);
      const float ec = pc[a];
      const float es = (kxs < 3) ? -ps[a] : ps[a];      // e^{+i kx x th}
      const int f = ky * 7 + kxs;
      rr += fr[f] * ec - fi[f] * es;
      ri += fr[f] * es + fi[f] * ec;
    }
    Rr[ky] = rr; Ri[ky] = ri;
  }
  float* o = Rtab + (size_t)(img * 512 + xx) * 8;
  const float k2s = 2.f * INV_N2;
  *reinterpret_cast<float4*>(o) =
      make_float4(Rr[0] * INV_N2, Rr[1] * k2s, Ri[1] * k2s, Rr[2] * k2s);
  *reinterpret_cast<float4*>(o + 4) =
      make_float4(Ri[2] * k2s, Rr[3] * k2s, Ri[3] * k2s, 0.f);
}

// ---------------- shared per-block prologue for K3/K4 (32-row tiles) --------
__device__ __forceinline__ void load_ctx(const float* __restrict__ Rtab, int img,
                                         int xi, int ybase, int tid,
                                         float (*yt)[6], float4 Ra[4], float4 Rb[4]) {
  if (tid < 32) {
    const int y = ybase + tid;
    float c1, s1;
    __sincosf(TWOPI_N * (float)y, &s1, &c1);
    const float c2 = c1 * c1 - s1 * s1, s2 = 2.f * c1 * s1;
    const float c3 = c1 * c2 - s1 * s2, s3 = s1 * c2 + c1 * s2;
    yt[tid][0] = c1; yt[tid][1] = s1;
    yt[tid][2] = c2; yt[tid][3] = s2;
    yt[tid][4] = c3; yt[tid][5] = s3;
  }
  const float* rt = Rtab + (size_t)(img * 512 + xi) * 8;
  #pragma unroll
  for (int j = 0; j < 4; ++j) {
    Ra[j] = *reinterpret_cast<const float4*>(rt + j * 8);
    Rb[j] = *reinterpret_cast<const float4*>(rt + j * 8 + 4);
  }
  __syncthreads();
}

__device__ __forceinline__ float recon(const float4& Ra, const float4& Rb,
                                       const float* yy) {
  float S = Ra.x;
  S = fmaf(Ra.y,  yy[0], S); S = fmaf(-Ra.z, yy[1], S);
  S = fmaf(Ra.w,  yy[2], S); S = fmaf(-Rb.x, yy[3], S);
  S = fmaf(Rb.y,  yy[4], S); S = fmaf(-Rb.z, yy[5], S);
  return S;
}

// ---------------- K3: global maxes + channel-0 x-copy (8-deep, NT stores) ---
__global__ __launch_bounds__(256) void k3_maxcopy(const float* __restrict__ x,
    const float* __restrict__ Rtab, unsigned int* __restrict__ maxes,
    float* __restrict__ out) {
  const int img = blockIdx.y;
  const int b = img / 3, c = img - b * 3;
  const int tid = threadIdx.x;
  const int xi = (tid & 127) * 4;
  const int p = tid >> 7;
  const int ybase = blockIdx.x * 32;
  __shared__ float yt[32][6];
  float4 Ra[4], Rb[4];
  load_ctx(Rtab, img, xi, ybase, tid, yt, Ra, Rb);
  const float* xim = x + (((size_t)img) << 18);
  float* o0 = out + (((size_t)(b * 9 + c)) << 18);
  float mlp = 0.f, mhp = 0.f;
  for (int g = 0; g < 2; ++g) {
    // batch: 8 independent loads in flight
    float4 xv[8];
    int yy[8];
    #pragma unroll
    for (int u = 0; u < 8; ++u) {
      yy[u] = (g * 8 + u) * 2 + p;
      xv[u] = *reinterpret_cast<const float4*>(xim + (ybase + yy[u]) * NN + xi);
    }
    // stores issued before dependent compute (NT: output never re-read)
    #pragma unroll
    for (int u = 0; u < 8; ++u) {
      f4v xvv = {xv[u].x, xv[u].y, xv[u].z, xv[u].w};
      __builtin_nontemporal_store(xvv,
          reinterpret_cast<f4v*>(o0 + (ybase + yy[u]) * NN + xi));
    }
    #pragma unroll
    for (int u = 0; u < 8; ++u) {
      float yv[6];
      #pragma unroll
      for (int q = 0; q < 6; ++q) yv[q] = yt[yy[u]][q];
      const float xe[4] = {xv[u].x, xv[u].y, xv[u].z, xv[u].w};
      #pragma unroll
      for (int j = 0; j < 4; ++j) {
        const float sig = recon(Ra[j], Rb[j], yv);
        mlp = fmaxf(mlp, fabsf(sig));
        mhp = fmaxf(mhp, fabsf(xe[j] - sig));
      }
    }
  }
  #pragma unroll
  for (int off = 32; off; off >>= 1) {
    mlp = fmaxf(mlp, __shfl_down(mlp, off));
    mhp = fmaxf(mhp, __shfl_down(mhp, off));
  }
  __shared__ float sm[8];
  const int lane = tid & 63, wv = tid >> 6;
  if (lane == 0) { sm[wv * 2] = mlp; sm[wv * 2 + 1] = mhp; }
  __syncthreads();
  if (tid == 0) {
    const float a  = fmaxf(fmaxf(sm[0], sm[2]), fmaxf(sm[4], sm[6]));
    const float bb = fmaxf(fmaxf(sm[1], sm[3]), fmaxf(sm[5], sm[7]));
    atomicMax(&maxes[0], __float_as_uint(a));   // nonneg floats: bit order == value order
    atomicMax(&maxes[1], __float_as_uint(bb));
  }
}

// ---------------- K4: lp/hp write (8-deep batches, NT stores) ----------------
__global__ __launch_bounds__(256) void k4_write(const float* __restrict__ x,
    const float* __restrict__ Rtab, const unsigned int* __restrict__ maxes,
    float* __restrict__ out) {
  const int img = blockIdx.y;
  const int b = img / 3, c = img - b * 3;
  const int tid = threadIdx.x;
  const int xi = (tid & 127) * 4;
  const int p = tid >> 7;
  const int ybase = blockIdx.x * 32;
  __shared__ float yt[32][6];
  float4 Ra[4], Rb[4];
  load_ctx(Rtab, img, xi, ybase, tid, yt, Ra, Rb);
  const float inv_lp = 1.f / __uint_as_float(maxes[0]);
  const float inv_hp = 1.f / __uint_as_float(maxes[1]);
  const float* xim = x + (((size_t)img) << 18);
  float* o1 = out + (((size_t)(b * 9 + 3 + c)) << 18);
  float* o2 = out + (((size_t)(b * 9 + 6 + c)) << 18);
  for (int g = 0; g < 2; ++g) {
    // batch: 8 independent loads in flight
    float4 xv[8];
    int yy[8];
    #pragma unroll
    for (int u = 0; u < 8; ++u) {
      yy[u] = (g * 8 + u) * 2 + p;
      xv[u] = *reinterpret_cast<const float4*>(xim + (ybase + yy[u]) * NN + xi);
    }
    #pragma unroll
    for (int u = 0; u < 8; ++u) {
      float yv[6];
      #pragma unroll
      for (int q = 0; q < 6; ++q) yv[q] = yt[yy[u]][q];
      const float xe[4] = {xv[u].x, xv[u].y, xv[u].z, xv[u].w};
      f4v lpv, hpv;
      #pragma unroll
      for (int j = 0; j < 4; ++j) {
        const float sig = recon(Ra[j], Rb[j], yv);
        lpv[j] = fabsf(sig) * inv_lp;
        hpv[j] = fabsf(xe[j] - sig) * inv_hp;
      }
      const int o = (ybase + yy[u]) * NN + xi;
      __builtin_nontemporal_store(lpv, reinterpret_cast<f4v*>(o1 + o));
      __builtin_nontemporal_store(hpv, reinterpret_cast<f4v*>(o2 + o));
    }
  }
}

extern "C" void kernel_launch(void* const* d_in, const int* in_sizes, int n_in,
                              void* d_out, int out_size, void* d_ws, size_t ws_size,
                              hipStream_t stream) {
  if (ws_size < (size_t)WS_NEEDED) return;  // loud failure instead of corruption
  const float* x = (const float*)d_in[0];
  float* out = (float*)d_out;
  char* ws = (char*)d_ws;
  float* G = (float*)(ws + G_OFF);
  float* Rtab = (float*)(ws + R_OFF);
  unsigned int* maxes = (unsigned int*)(ws + MAX_OFF);

  k1_rowfft<<<dim3(32, IMGS), 256, 0, stream>>>(x, G, maxes);
  k2_colfft<<<dim3(IMGS), 512, 0, stream>>>(G, Rtab);
  k3_maxcopy<<<dim3(16, IMGS), 256, 0, stream>>>(x, Rtab, maxes, out);
  k4_write<<<dim3(16, IMGS), 256, 0, stream>>>(x, Rtab, maxes, out);
}